// Round 1
// baseline (69.504 us; speedup 1.0000x reference)
//
#include <hip/hip_runtime.h>

// Problem constants (fixed by setup_inputs)
#define B 4
#define C 32
#define H 128
#define W 128
#define K 128
#define V 16           // C/2 vertices
#define HW (H * W)
#define OFFSET 100.0f

// Kernel A: one block per polygon pair (pred, gt). 128 threads = 1 scanline row each.
// Builds 128-bit even-odd parity masks per row via XOR of prefix masks, popcounts,
// reduces to inter/union, writes iou * mask into poly_out[b*K+k].
__global__ __launch_bounds__(128) void poly_iou_kernel(
    const float* __restrict__ output,   // [B,C,H,W]
    const int*   __restrict__ mask,     // [B,K]
    const int*   __restrict__ ind,      // [B,K]
    const float* __restrict__ target,   // [B,C,K]
    float* __restrict__ poly_out)       // [B*K]
{
    const int bk  = blockIdx.x;
    const int b   = bk / K;
    const int k   = bk - b * K;
    const int tid = threadIdx.x;

    __shared__ float sxp[V], syp[V], sxg[V], syg[V];
    __shared__ int   s_acc[3];   // pin_sum, gin_sum, inter_sum

    if (tid < 3) s_acc[tid] = 0;

    if (tid < C) {
        // pred vertices: gather output[b, c, ind[b,k]]
        const int idx = ind[b * K + k];
        const float val = truncf(output[(size_t)b * C * HW + (size_t)tid * HW + idx]) + OFFSET;
        if (tid & 1) syp[tid >> 1] = val; else sxp[tid >> 1] = val;
    } else if (tid < 2 * C) {
        const int c = tid - C;
        const float val = truncf(target[(size_t)b * C * K + (size_t)c * K + k]) + OFFSET;
        if (c & 1) syg[c >> 1] = val; else sxg[c >> 1] = val;
    }
    __syncthreads();

    const float pyf = (float)tid;   // scanline row
    unsigned long long pl0 = 0, pl1 = 0, gl0 = 0, gl1 = 0;

    #pragma unroll
    for (int v = 0; v < V; ++v) {
        const int v2 = (v + 1) & (V - 1);
        // pred polygon edge
        {
            const float y1 = syp[v], y2 = syp[v2];
            if ((y1 <= pyf) != (y2 <= pyf)) {
                const float x1 = sxp[v], x2 = sxp[v2];
                const float t  = __fdiv_rn(pyf - y1, y2 - y1);
                const float xi = __fadd_rn(x1, __fmul_rn(t, x2 - x1));
                int n = (int)ceilf(xi);
                n = n < 0 ? 0 : (n > 128 ? 128 : n);
                pl0 ^= (n >= 64) ? ~0ull : ((1ull << n) - 1ull);
                pl1 ^= (n <= 64) ? 0ull : ((n >= 128) ? ~0ull : ((1ull << (n - 64)) - 1ull));
            }
        }
        // gt polygon edge
        {
            const float y1 = syg[v], y2 = syg[v2];
            if ((y1 <= pyf) != (y2 <= pyf)) {
                const float x1 = sxg[v], x2 = sxg[v2];
                const float t  = __fdiv_rn(pyf - y1, y2 - y1);
                const float xi = __fadd_rn(x1, __fmul_rn(t, x2 - x1));
                int n = (int)ceilf(xi);
                n = n < 0 ? 0 : (n > 128 ? 128 : n);
                gl0 ^= (n >= 64) ? ~0ull : ((1ull << n) - 1ull);
                gl1 ^= (n <= 64) ? 0ull : ((n >= 128) ? ~0ull : ((1ull << (n - 64)) - 1ull));
            }
        }
    }

    int pin = __popcll(pl0) + __popcll(pl1);
    int gin = __popcll(gl0) + __popcll(gl1);
    int itr = __popcll(pl0 & gl0) + __popcll(pl1 & gl1);

    // wave-64 butterfly, then 2-wave combine via LDS atomics
    #pragma unroll
    for (int off = 32; off; off >>= 1) {
        pin += __shfl_down(pin, off, 64);
        gin += __shfl_down(gin, off, 64);
        itr += __shfl_down(itr, off, 64);
    }
    if ((tid & 63) == 0) {
        atomicAdd(&s_acc[0], pin);
        atomicAdd(&s_acc[1], gin);
        atomicAdd(&s_acc[2], itr);
    }
    __syncthreads();

    if (tid == 0) {
        const float inter = (float)s_acc[2];
        const float uni   = (float)(s_acc[0] + s_acc[1]) - inter;
        const float iou   = inter / (uni + 0.0001f);
        poly_out[bk] = iou * (float)mask[b * K + k];
    }
}

// Kernel B: reduce 512 per-polygon iou*m values + mask sum -> scalar loss.
__global__ __launch_bounds__(512) void finalize_kernel(
    const float* __restrict__ poly,   // [B*K]
    const int*   __restrict__ mask,   // [B*K]
    float* __restrict__ out)
{
    const int tid = threadIdx.x;      // 512 threads, one per polygon
    float s = poly[tid];
    float m = (float)mask[tid];

    #pragma unroll
    for (int off = 32; off; off >>= 1) {
        s += __shfl_down(s, off, 64);
        m += __shfl_down(m, off, 64);
    }

    __shared__ float ss[8], sm[8];
    const int w = tid >> 6;
    if ((tid & 63) == 0) { ss[w] = s; sm[w] = m; }
    __syncthreads();

    if (tid == 0) {
        float S = 0.0f, M = 0.0f;
        #pragma unroll
        for (int i = 0; i < 8; ++i) { S += ss[i]; M += sm[i]; }
        out[0] = 1.0f - S / (M + 0.0001f);
    }
}

extern "C" void kernel_launch(void* const* d_in, const int* in_sizes, int n_in,
                              void* d_out, int out_size, void* d_ws, size_t ws_size,
                              hipStream_t stream) {
    const float* output = (const float*)d_in[0];
    const int*   mask   = (const int*)d_in[1];
    const int*   ind    = (const int*)d_in[2];
    const float* target = (const float*)d_in[3];

    float* poly = (float*)d_ws;   // [B*K] floats scratch, fully overwritten each call

    poly_iou_kernel<<<B * K, 128, 0, stream>>>(output, mask, ind, target, poly);
    finalize_kernel<<<1, 512, 0, stream>>>(poly, mask, (float*)d_out);
}